// Round 2
// baseline (462.267 us; speedup 1.0000x reference)
//
#include <hip/hip_runtime.h>
#include <hip/hip_bf16.h>

#pragma clang fp contract(off)

// ---------------- problem constants ----------------
#define BATCH 32
#define NPOS  22743          // sum f*f*3 over {19,38,76}
#define ROW   85             // 5 + 80 classes
#define KTOP  300
#define KPAD  512
#define CHUNKS 12            // blocks per image in extract (12*2048 >= 22743)

// output layout (floats), concatenated in reference return order
#define OFF_IDS    0
#define OFF_BOXES  (BATCH*KTOP)                    // 9600
#define OFF_LABELS (OFF_BOXES + BATCH*KTOP*4)      // 48000
#define OFF_SCORES (OFF_LABELS + BATCH*KTOP)       // 57600

// workspace layout (bytes)
#define WS_KEYS   0
#define WS_HIST   (BATCH*NPOS*4)                   // 2,911,104
#define WS_SELIDX (WS_HIST + BATCH*256*4)
#define WS_SELKEY (WS_SELIDX + BATCH*KTOP*4)
#define WS_LABELS (WS_SELKEY + BATCH*KTOP*4)

__device__ __forceinline__ float sigmoidf_ref(float x) {
    return 1.0f / (1.0f + expf(-x));
}

// ---------------------------------------------------------------------------
// Kernel A: extract conf key per (b,n) + pass-0 (top byte) histogram per image.
// key = conf > 0.5f ? bits(conf) : 0   (conf positive -> bits monotone)
// ---------------------------------------------------------------------------
__global__ __launch_bounds__(256) void k_extract(const float* __restrict__ p,
                                                 unsigned* __restrict__ keys,
                                                 unsigned* __restrict__ hist) {
    __shared__ unsigned h[256];
    const int t = threadIdx.x;
    h[t] = 0;
    __syncthreads();
    const int b = blockIdx.x / CHUNKS;
    const int chunk = blockIdx.x % CHUNKS;
    const int base = chunk * 2048;
    for (int it = 0; it < 8; ++it) {
        int n = base + it * 256 + t;
        bool part = (n < NPOS);
        unsigned key = 0, bin = 0;
        if (part) {
            float x = p[((size_t)b * NPOS + n) * ROW + 4];
            float cf = sigmoidf_ref(x);
            key = (cf > 0.5f) ? __float_as_uint(cf) : 0u;
            keys[(size_t)b * NPOS + n] = key;
            bin = key >> 24;
        }
        // wave-aggregated LDS histogram (bins are highly concentrated here)
        unsigned long long todo = __ballot(part);
        while (todo) {
            int leader = __ffsll((unsigned long long)todo) - 1;
            unsigned lbin = __shfl(bin, leader);
            unsigned long long same = __ballot(part && (bin == lbin));
            if ((t & 63) == leader) atomicAdd(&h[lbin], (unsigned)__popcll(same));
            todo &= ~same;
        }
    }
    __syncthreads();
    if (h[t]) atomicAdd(&hist[b * 256 + t], h[t]);
}

// ---------------------------------------------------------------------------
// Kernel B: per-image exact top-300 (radix-select + bitonic sort), stable
// (key desc, index asc) to match lax.top_k tie semantics.
// ---------------------------------------------------------------------------
__global__ __launch_bounds__(256) void k_select(const unsigned* __restrict__ keys,
                                                const unsigned* __restrict__ hist,
                                                int* __restrict__ sel_idx,
                                                unsigned* __restrict__ sel_key) {
    const int b = blockIdx.x;
    const int t = threadIdx.x;
    __shared__ unsigned h[256];
    __shared__ unsigned sc[256];
    __shared__ unsigned bcast_bin, bcast_R;
    __shared__ int cnt, ovf;
    __shared__ unsigned long long arr[KPAD];
    const unsigned* kb = keys + (size_t)b * NPOS;

    unsigned prefix = 0;
    unsigned R = KTOP;

    for (int pass = 0; pass < 4; ++pass) {
        const int shift = 24 - 8 * pass;
        if (pass == 0) {
            h[t] = hist[b * 256 + t];
            __syncthreads();
        } else {
            h[t] = 0;
            __syncthreads();
            for (int n = t; n < NPOS; n += 256) {
                unsigned u = kb[n];
                if ((u >> (shift + 8)) == prefix) atomicAdd(&h[(u >> shift) & 255], 1u);
            }
            __syncthreads();
        }
        // suffix-inclusive sum: sc[v] = sum_{w>=v} h[w]
        sc[t] = h[t];
        __syncthreads();
        for (int off = 1; off < 256; off <<= 1) {
            unsigned add = (t + off < 256) ? sc[t + off] : 0u;
            __syncthreads();
            sc[t] += add;
            __syncthreads();
        }
        unsigned snext = (t < 255) ? sc[t + 1] : 0u;
        if (sc[t] >= R && snext < R) { bcast_bin = (unsigned)t; bcast_R = R - snext; }
        __syncthreads();
        prefix = (prefix << 8) | bcast_bin;
        R = bcast_R;
        __syncthreads();
    }
    const unsigned T = prefix;  // exact 300th key; R = #equals needed

    if (t == 0) { cnt = 0; ovf = 0; }
    for (int e = t; e < KPAD; e += 256) arr[e] = 0ull;
    __syncthreads();
    for (int n = t; n < NPOS; n += 256) {
        unsigned u = kb[n];
        if (u >= T) {
            int pos = atomicAdd(&cnt, 1);
            if (pos < KPAD) arr[pos] = ((unsigned long long)u << 32) | (unsigned)(~n);
            else ovf = 1;
        }
    }
    __syncthreads();
    if (ovf) {  // degenerate tie storm: redo greaters (always < 300), serial equals
        if (t == 0) cnt = 0;
        __syncthreads();
        for (int e = t; e < KPAD; e += 256) arr[e] = 0ull;
        __syncthreads();
        for (int n = t; n < NPOS; n += 256) {
            unsigned u = kb[n];
            if (u > T) {
                int pos = atomicAdd(&cnt, 1);
                arr[pos] = ((unsigned long long)u << 32) | (unsigned)(~n);
            }
        }
        __syncthreads();
        if (t == 0) {
            int c = cnt;
            for (int n = 0; n < NPOS && c < KTOP; ++n)
                if (kb[n] == T) arr[c++] = ((unsigned long long)T << 32) | (unsigned)(~n);
        }
        __syncthreads();
    }
    // ascending bitonic sort of 512 u64; pads(0) sort first, real entries last
    for (unsigned kk = 2; kk <= KPAD; kk <<= 1)
        for (unsigned j = kk >> 1; j > 0; j >>= 1) {
            __syncthreads();
            for (unsigned e = t; e < KPAD; e += 256) {
                unsigned partner = e ^ j;
                if (partner > e) {
                    bool up = ((e & kk) == 0);
                    unsigned long long a = arr[e], bb = arr[partner];
                    if (up ? (a > bb) : (a < bb)) { arr[e] = bb; arr[partner] = a; }
                }
            }
        }
    __syncthreads();
    for (int e = t; e < KTOP; e += 256) {
        unsigned long long v = arr[KPAD - 1 - e];  // descending
        sel_idx[b * KTOP + e] = (int)(~(unsigned)v);
        sel_key[b * KTOP + e] = (unsigned)(v >> 32);
    }
}

// ---------------------------------------------------------------------------
// Kernel C: gather+decode selected rows. One wave per (b,k).
// ---------------------------------------------------------------------------
__global__ __launch_bounds__(256) void k_decode(const float* __restrict__ p,
                                                const float* __restrict__ ancs,
                                                const float* __restrict__ fsz,
                                                const int* __restrict__ sel_idx,
                                                int* __restrict__ labels,
                                                float* __restrict__ out) {
    const int wid = (int)((blockIdx.x * blockDim.x + threadIdx.x) >> 6);
    const int lane = threadIdx.x & 63;
    if (wid >= BATCH * KTOP) return;
    const int b = wid / KTOP, k = wid % KTOP;
    const int n = sel_idx[b * KTOP + k];
    const size_t base = ((size_t)b * NPOS + n) * ROW;

    float v1 = p[base + lane];
    float v2 = (lane < 21) ? p[base + 64 + lane] : -INFINITY;

    // class argmax (raw logits; sigmoid is monotone), ties -> lower class
    float bv = -INFINITY; int bc = 1 << 20;
    if (lane >= 5) { bv = v1; bc = lane - 5; }            // classes 0..58
    if (lane < 21) {
        int c2 = 59 + lane;                                // classes 59..79
        if (v2 > bv || (v2 == bv && c2 < bc)) { bv = v2; bc = c2; }
    }
    for (int d = 32; d; d >>= 1) {
        float ov = __shfl_xor(bv, d);
        int   oc = __shfl_xor(bc, d);
        if (ov > bv || (ov == bv && oc < bc)) { bv = ov; bc = oc; }
    }
    const int label = bc + 1;

    float t0 = __shfl(v1, 0), t1 = __shfl(v1, 1), t2 = __shfl(v1, 2), t3 = __shfl(v1, 3);
    if (lane == 0) {
        float f0 = fsz[(size_t)n * 2 + 0], f1 = fsz[(size_t)n * 2 + 1];
        float a0 = ancs[(size_t)n * 4 + 0], a1 = ancs[(size_t)n * 4 + 1];
        float a2 = ancs[(size_t)n * 4 + 2], a3 = ancs[(size_t)n * 4 + 3];
        float cx = sigmoidf_ref(t0) / f0 + a0;
        float cy = sigmoidf_ref(t1) / f1 + a1;
        float w  = expf(t2) * a2;
        float hh = expf(t3) * a3;
        float* ob = out + OFF_BOXES + (size_t)(b * KTOP + k) * 4;
        ob[0] = cx - w * 0.5f;
        ob[1] = cy - hh * 0.5f;
        ob[2] = cx + w * 0.5f;
        ob[3] = cy + hh * 0.5f;
        out[OFF_IDS + b * KTOP + k] = (float)b;
        labels[b * KTOP + k] = label;
    }
}

// ---------------------------------------------------------------------------
// Kernel D: per-image label-offset NMS (greedy scan over 300, bitmask form)
// + final scores/labels outputs.
// ---------------------------------------------------------------------------
__global__ __launch_bounds__(256) void k_nms(const float* __restrict__ boxes,
                                             const int* __restrict__ labels,
                                             const unsigned* __restrict__ sel_key,
                                             float* __restrict__ out) {
    const int b = blockIdx.x, t = threadIdx.x;
    __shared__ float bx[KTOP][4];
    __shared__ float area[KTOP];
    __shared__ float score[KTOP];
    __shared__ int   lab[KTOP];
    __shared__ int   validb[KTOP];
    __shared__ unsigned long long O[KTOP * 5];
    __shared__ unsigned long long vb[5];
    __shared__ unsigned long long kw[5];

    for (int k = t; k < KTOP; k += 256) {
        const float* p4 = boxes + (size_t)(b * KTOP + k) * 4;
        int L = labels[b * KTOP + k];
        float off = (float)L * 4.0f;
        float l = p4[0] + off, tp = p4[1] + off, r = p4[2] + off, bt = p4[3] + off;
        bx[k][0] = l; bx[k][1] = tp; bx[k][2] = r; bx[k][3] = bt;
        area[k] = fmaxf(r - l, 0.0f) * fmaxf(bt - tp, 0.0f);
        lab[k] = L;
        unsigned key = sel_key[b * KTOP + k];
        validb[k] = (key > 0x3F000000u) ? 1 : 0;   // conf > 0.5f (positive bits)
        score[k] = __uint_as_float(key);           // == top_scores exactly
    }
    __syncthreads();

    // overlap bitmask, lower triangle only (keep[j] can only matter for j<i)
    for (int i = t; i < KTOP; i += 256) {
        float li = bx[i][0], ti = bx[i][1], ri = bx[i][2], bi = bx[i][3], ai = area[i];
        for (int q = 0; q < 5; ++q) {
            unsigned long long wq = 0ull;
            int j0 = q * 64, j1 = min(i, j0 + 64);
            for (int j = j0; j < j1; ++j) {
                float lt0 = fmaxf(li, bx[j][0]);
                float lt1 = fmaxf(ti, bx[j][1]);
                float rb0 = fminf(ri, bx[j][2]);
                float rb1 = fminf(bi, bx[j][3]);
                float ww = fmaxf(rb0 - lt0, 0.0f);
                float hh = fmaxf(rb1 - lt1, 0.0f);
                float inter = ww * hh;
                float iou = inter / (((ai + area[j]) - inter) + 1e-7f);
                if (iou > 0.3f) wq |= 1ull << (j & 63);
            }
            O[i * 5 + q] = wq;
        }
    }
    if (t < 5) {
        unsigned long long v = 0ull;
        for (int j = 0; j < 64; ++j) {
            int idx = t * 64 + j;
            if (idx < KTOP && validb[idx]) v |= 1ull << j;
        }
        vb[t] = v;
    }
    __syncthreads();

    // serial greedy scan: wave 0, lanes 0..4 own keep-bit words, prefetch next row
    if (t < 64) {
        const int lane = t;
        unsigned long long kwl = 0ull;
        unsigned long long vbl = (lane < 5) ? vb[lane] : 0ull;
        unsigned long long cur = (lane < 5) ? O[lane] : 0ull;
        for (int i = 0; i < KTOP; ++i) {
            unsigned long long nxt = (lane < 5 && i < KTOP - 1) ? O[(i + 1) * 5 + lane] : 0ull;
            bool sup = __any((cur & kwl) != 0ull);
            if (lane == (i >> 6)) {
                bool v = (vbl >> (i & 63)) & 1ull;
                if (v && !sup) kwl |= 1ull << (i & 63);
            }
            cur = nxt;
        }
        if (lane < 5) kw[lane] = kwl;
    }
    __syncthreads();

    for (int k = t; k < KTOP; k += 256) {
        bool kp = (kw[k >> 6] >> (k & 63)) & 1ull;
        out[OFF_SCORES + b * KTOP + k] = kp ? score[k] : 0.0f;
        out[OFF_LABELS + b * KTOP + k] = kp ? (float)lab[k] : 0.0f;
    }
}

// ---------------------------------------------------------------------------
extern "C" void kernel_launch(void* const* d_in, const int* in_sizes, int n_in,
                              void* d_out, int out_size, void* d_ws, size_t ws_size,
                              hipStream_t stream) {
    const float* p    = (const float*)d_in[0];   // [B,N,85]
    const float* ancs = (const float*)d_in[1];   // [N,4]
    const float* fsz  = (const float*)d_in[2];   // [N,2]
    float* out = (float*)d_out;

    char* w = (char*)d_ws;
    unsigned* keys    = (unsigned*)(w + WS_KEYS);
    unsigned* hist    = (unsigned*)(w + WS_HIST);
    int*      sel_idx = (int*)(w + WS_SELIDX);
    unsigned* sel_key = (unsigned*)(w + WS_SELKEY);
    int*      labels  = (int*)(w + WS_LABELS);

    hipMemsetAsync(hist, 0, BATCH * 256 * 4, stream);
    hipLaunchKernelGGL(k_extract, dim3(BATCH * CHUNKS), dim3(256), 0, stream, p, keys, hist);
    hipLaunchKernelGGL(k_select, dim3(BATCH), dim3(256), 0, stream, keys, hist, sel_idx, sel_key);
    hipLaunchKernelGGL(k_decode, dim3((BATCH * KTOP + 3) / 4), dim3(256), 0, stream,
                       p, ancs, fsz, sel_idx, labels, out);
    hipLaunchKernelGGL(k_nms, dim3(BATCH), dim3(256), 0, stream, out + OFF_BOXES, labels, sel_key, out);
}

// Round 3
// 453.871 us; speedup vs baseline: 1.0185x; 1.0185x over previous
//
#include <hip/hip_runtime.h>
#include <hip/hip_bf16.h>

#pragma clang fp contract(off)

// ---------------- problem constants ----------------
#define BATCH 32
#define NPOS  22743          // sum f*f*3 over {19,38,76}
#define ROW   85             // 5 + 80 classes
#define KTOP  300
#define KPAD  512

// output layout (floats), concatenated in reference return order
#define OFF_IDS    0
#define OFF_BOXES  (BATCH*KTOP)                    // 9600
#define OFF_LABELS (OFF_BOXES + BATCH*KTOP*4)      // 48000
#define OFF_SCORES (OFF_LABELS + BATCH*KTOP)       // 57600

// workspace layout (bytes)
#define WS_KEYS   0
#define WS_SELIDX (BATCH*NPOS*4)                   // 2,911,104
#define WS_SELKEY (WS_SELIDX + BATCH*KTOP*4)
#define WS_LABELS (WS_SELKEY + BATCH*KTOP*4)

__device__ __forceinline__ float sigmoidf_ref(float x) {
    return 1.0f / (1.0f + expf(-x));
}

// ---------------------------------------------------------------------------
// Kernel A: conf key per (b,n). Valid conf ∈ (0.5,1) always has float bits
// 0x3F000001..0x3F7FFFFF (exponent 0x7E), so the top byte is constant ->
// store only the low 24 bits (0 = invalid). Pure streaming kernel.
// ---------------------------------------------------------------------------
__global__ __launch_bounds__(256) void k_extract(const float* __restrict__ p,
                                                 unsigned* __restrict__ keys) {
    const int g = blockIdx.x * 256 + threadIdx.x;
    if (g < BATCH * NPOS) {
        float x = p[(size_t)g * ROW + 4];
        float cf = sigmoidf_ref(x);
        keys[g] = (cf > 0.5f) ? (__float_as_uint(cf) & 0x00FFFFFFu) : 0u;
    }
}

// ---------------------------------------------------------------------------
// Kernel B: per-image exact top-300 (3-byte radix-select + bitonic sort),
// stable (key desc, index asc) to match lax.top_k tie semantics.
// ---------------------------------------------------------------------------
__global__ __launch_bounds__(256) void k_select(const unsigned* __restrict__ keys,
                                                int* __restrict__ sel_idx,
                                                unsigned* __restrict__ sel_key) {
    const int b = blockIdx.x;
    const int t = threadIdx.x;
    __shared__ unsigned h[256];
    __shared__ unsigned sc[256];
    __shared__ unsigned bcast_bin, bcast_R;
    __shared__ int cnt, ovf;
    __shared__ unsigned long long arr[KPAD];
    const unsigned* kb = keys + (size_t)b * NPOS;

    unsigned prefix = 0;
    unsigned R = KTOP;

    for (int pass = 0; pass < 3; ++pass) {
        const int shift = 16 - 8 * pass;
        h[t] = 0;
        __syncthreads();
        for (int n = t; n < NPOS; n += 256) {
            unsigned u = kb[n];
            if (pass == 0 || (u >> (shift + 8)) == prefix)
                atomicAdd(&h[(u >> shift) & 255], 1u);
        }
        __syncthreads();
        // suffix-inclusive sum: sc[v] = sum_{w>=v} h[w]
        sc[t] = h[t];
        __syncthreads();
        for (int off = 1; off < 256; off <<= 1) {
            unsigned add = (t + off < 256) ? sc[t + off] : 0u;
            __syncthreads();
            sc[t] += add;
            __syncthreads();
        }
        unsigned snext = (t < 255) ? sc[t + 1] : 0u;
        if (sc[t] >= R && snext < R) { bcast_bin = (unsigned)t; bcast_R = R - snext; }
        __syncthreads();
        prefix = (prefix << 8) | bcast_bin;
        R = bcast_R;
        __syncthreads();
    }
    const unsigned T = prefix;  // exact 300th 24-bit key

    if (t == 0) { cnt = 0; ovf = 0; }
    for (int e = t; e < KPAD; e += 256) arr[e] = 0ull;
    __syncthreads();
    for (int n = t; n < NPOS; n += 256) {
        unsigned u = kb[n];
        if (u >= T) {
            int pos = atomicAdd(&cnt, 1);
            if (pos < KPAD) arr[pos] = ((unsigned long long)u << 32) | (unsigned)(~n);
            else ovf = 1;
        }
    }
    __syncthreads();
    if (ovf) {  // degenerate tie storm: redo strict-greaters, serial equals
        if (t == 0) cnt = 0;
        __syncthreads();
        for (int e = t; e < KPAD; e += 256) arr[e] = 0ull;
        __syncthreads();
        for (int n = t; n < NPOS; n += 256) {
            unsigned u = kb[n];
            if (u > T) {
                int pos = atomicAdd(&cnt, 1);
                if (pos < KPAD) arr[pos] = ((unsigned long long)u << 32) | (unsigned)(~n);
            }
        }
        __syncthreads();
        if (t == 0) {
            int c = min(cnt, KPAD - 1);
            for (int n = 0; n < NPOS && c < KTOP; ++n)
                if (kb[n] == T) arr[c++] = ((unsigned long long)T << 32) | (unsigned)(~n);
        }
        __syncthreads();
    }
    // ascending bitonic sort of 512 u64; pads(0) sort first, real entries last
    for (unsigned kk = 2; kk <= KPAD; kk <<= 1)
        for (unsigned j = kk >> 1; j > 0; j >>= 1) {
            __syncthreads();
            for (unsigned e = t; e < KPAD; e += 256) {
                unsigned partner = e ^ j;
                if (partner > e) {
                    bool up = ((e & kk) == 0);
                    unsigned long long a = arr[e], bb = arr[partner];
                    if (up ? (a > bb) : (a < bb)) { arr[e] = bb; arr[partner] = a; }
                }
            }
        }
    __syncthreads();
    for (int e = t; e < KTOP; e += 256) {
        unsigned long long v = arr[KPAD - 1 - e];  // descending
        sel_idx[b * KTOP + e] = (int)(~(unsigned)v);
        sel_key[b * KTOP + e] = (unsigned)(v >> 32);
    }
}

// ---------------------------------------------------------------------------
// Kernel C: gather+decode selected rows. One wave per (b,k).
// ---------------------------------------------------------------------------
__global__ __launch_bounds__(256) void k_decode(const float* __restrict__ p,
                                                const float* __restrict__ ancs,
                                                const float* __restrict__ fsz,
                                                const int* __restrict__ sel_idx,
                                                int* __restrict__ labels,
                                                float* __restrict__ out) {
    const int wid = (int)((blockIdx.x * blockDim.x + threadIdx.x) >> 6);
    const int lane = threadIdx.x & 63;
    if (wid >= BATCH * KTOP) return;
    const int b = wid / KTOP, k = wid % KTOP;
    const int n = sel_idx[b * KTOP + k];
    const size_t base = ((size_t)b * NPOS + n) * ROW;

    float v1 = p[base + lane];
    float v2 = (lane < 21) ? p[base + 64 + lane] : -INFINITY;

    // class argmax (raw logits; sigmoid is monotone), ties -> lower class
    float bv = -INFINITY; int bc = 1 << 20;
    if (lane >= 5) { bv = v1; bc = lane - 5; }            // classes 0..58
    if (lane < 21) {
        int c2 = 59 + lane;                                // classes 59..79
        if (v2 > bv || (v2 == bv && c2 < bc)) { bv = v2; bc = c2; }
    }
    for (int d = 32; d; d >>= 1) {
        float ov = __shfl_xor(bv, d);
        int   oc = __shfl_xor(bc, d);
        if (ov > bv || (ov == bv && oc < bc)) { bv = ov; bc = oc; }
    }
    const int label = bc + 1;

    float t0 = __shfl(v1, 0), t1 = __shfl(v1, 1), t2 = __shfl(v1, 2), t3 = __shfl(v1, 3);
    if (lane == 0) {
        float f0 = fsz[(size_t)n * 2 + 0], f1 = fsz[(size_t)n * 2 + 1];
        float a0 = ancs[(size_t)n * 4 + 0], a1 = ancs[(size_t)n * 4 + 1];
        float a2 = ancs[(size_t)n * 4 + 2], a3 = ancs[(size_t)n * 4 + 3];
        float cx = sigmoidf_ref(t0) / f0 + a0;
        float cy = sigmoidf_ref(t1) / f1 + a1;
        float w  = expf(t2) * a2;
        float hh = expf(t3) * a3;
        float* ob = out + OFF_BOXES + (size_t)(b * KTOP + k) * 4;
        ob[0] = cx - w * 0.5f;
        ob[1] = cy - hh * 0.5f;
        ob[2] = cx + w * 0.5f;
        ob[3] = cy + hh * 0.5f;
        out[OFF_IDS + b * KTOP + k] = (float)b;
        labels[b * KTOP + k] = label;
    }
}

// ---------------------------------------------------------------------------
// Kernel D: per-image label-offset NMS (greedy scan over 300, bitmask form)
// + final scores/labels outputs.
// ---------------------------------------------------------------------------
__global__ __launch_bounds__(256) void k_nms(const float* __restrict__ boxes,
                                             const int* __restrict__ labels,
                                             const unsigned* __restrict__ sel_key,
                                             float* __restrict__ out) {
    const int b = blockIdx.x, t = threadIdx.x;
    __shared__ float bx[KTOP][4];
    __shared__ float area[KTOP];
    __shared__ float score[KTOP];
    __shared__ int   lab[KTOP];
    __shared__ int   validb[KTOP];
    __shared__ unsigned long long O[KTOP * 5];
    __shared__ unsigned long long vb[5];
    __shared__ unsigned long long kw[5];

    for (int k = t; k < KTOP; k += 256) {
        const float* p4 = boxes + (size_t)(b * KTOP + k) * 4;
        int L = labels[b * KTOP + k];
        float off = (float)L * 4.0f;
        float l = p4[0] + off, tp = p4[1] + off, r = p4[2] + off, bt = p4[3] + off;
        bx[k][0] = l; bx[k][1] = tp; bx[k][2] = r; bx[k][3] = bt;
        area[k] = fmaxf(r - l, 0.0f) * fmaxf(bt - tp, 0.0f);
        lab[k] = L;
        unsigned key = sel_key[b * KTOP + k];
        validb[k] = (key != 0u) ? 1 : 0;                     // conf > 0.5
        score[k] = __uint_as_float(key | 0x3F000000u);       // exact top_scores
    }
    __syncthreads();

    // overlap bitmask, lower triangle only (keep[j] can only matter for j<i)
    for (int i = t; i < KTOP; i += 256) {
        float li = bx[i][0], ti = bx[i][1], ri = bx[i][2], bi = bx[i][3], ai = area[i];
        for (int q = 0; q < 5; ++q) {
            unsigned long long wq = 0ull;
            int j0 = q * 64, j1 = min(i, j0 + 64);
            for (int j = j0; j < j1; ++j) {
                float lt0 = fmaxf(li, bx[j][0]);
                float lt1 = fmaxf(ti, bx[j][1]);
                float rb0 = fminf(ri, bx[j][2]);
                float rb1 = fminf(bi, bx[j][3]);
                float ww = fmaxf(rb0 - lt0, 0.0f);
                float hh = fmaxf(rb1 - lt1, 0.0f);
                float inter = ww * hh;
                float iou = inter / (((ai + area[j]) - inter) + 1e-7f);
                if (iou > 0.3f) wq |= 1ull << (j & 63);
            }
            O[i * 5 + q] = wq;
        }
    }
    if (t < 5) {
        unsigned long long v = 0ull;
        for (int j = 0; j < 64; ++j) {
            int idx = t * 64 + j;
            if (idx < KTOP && validb[idx]) v |= 1ull << j;
        }
        vb[t] = v;
    }
    __syncthreads();

    // serial greedy scan: wave 0, lanes 0..4 own keep-bit words, prefetch next row
    if (t < 64) {
        const int lane = t;
        unsigned long long kwl = 0ull;
        unsigned long long vbl = (lane < 5) ? vb[lane] : 0ull;
        unsigned long long cur = (lane < 5) ? O[lane] : 0ull;
        for (int i = 0; i < KTOP; ++i) {
            unsigned long long nxt = (lane < 5 && i < KTOP - 1) ? O[(i + 1) * 5 + lane] : 0ull;
            bool sup = __any((cur & kwl) != 0ull);
            if (lane == (i >> 6)) {
                bool v = (vbl >> (i & 63)) & 1ull;
                if (v && !sup) kwl |= 1ull << (i & 63);
            }
            cur = nxt;
        }
        if (lane < 5) kw[lane] = kwl;
    }
    __syncthreads();

    for (int k = t; k < KTOP; k += 256) {
        bool kp = (kw[k >> 6] >> (k & 63)) & 1ull;
        out[OFF_SCORES + b * KTOP + k] = kp ? score[k] : 0.0f;
        out[OFF_LABELS + b * KTOP + k] = kp ? (float)lab[k] : 0.0f;
    }
}

// ---------------------------------------------------------------------------
extern "C" void kernel_launch(void* const* d_in, const int* in_sizes, int n_in,
                              void* d_out, int out_size, void* d_ws, size_t ws_size,
                              hipStream_t stream) {
    const float* p    = (const float*)d_in[0];   // [B,N,85]
    const float* ancs = (const float*)d_in[1];   // [N,4]
    const float* fsz  = (const float*)d_in[2];   // [N,2]
    float* out = (float*)d_out;

    char* w = (char*)d_ws;
    unsigned* keys    = (unsigned*)(w + WS_KEYS);
    int*      sel_idx = (int*)(w + WS_SELIDX);
    unsigned* sel_key = (unsigned*)(w + WS_SELKEY);
    int*      labels  = (int*)(w + WS_LABELS);

    const int total = BATCH * NPOS;
    hipLaunchKernelGGL(k_extract, dim3((total + 255) / 256), dim3(256), 0, stream, p, keys);
    hipLaunchKernelGGL(k_select, dim3(BATCH), dim3(256), 0, stream, keys, sel_idx, sel_key);
    hipLaunchKernelGGL(k_decode, dim3((BATCH * KTOP + 3) / 4), dim3(256), 0, stream,
                       p, ancs, fsz, sel_idx, labels, out);
    hipLaunchKernelGGL(k_nms, dim3(BATCH), dim3(256), 0, stream, out + OFF_BOXES, labels, sel_key, out);
}

// Round 4
// 385.221 us; speedup vs baseline: 1.2000x; 1.1782x over previous
//
#include <hip/hip_runtime.h>
#include <hip/hip_bf16.h>

#pragma clang fp contract(off)

// ---------------- problem constants ----------------
#define BATCH 32
#define NPOS  22743          // sum f*f*3 over {19,38,76}
#define NPOSP 22744          // padded stride (16B-aligned uint4 rows); pad key = 0
#define N4P   (NPOSP/4)      // 5686 uint4 per image
#define ROW   85             // 5 + 80 classes
#define KTOP  300
#define KPAD  512

// output layout (floats), concatenated in reference return order
#define OFF_IDS    0
#define OFF_BOXES  (BATCH*KTOP)                    // 9600
#define OFF_LABELS (OFF_BOXES + BATCH*KTOP*4)      // 48000
#define OFF_SCORES (OFF_LABELS + BATCH*KTOP)       // 57600

// workspace layout (bytes)
#define WS_KEYS   0
#define WS_SELIDX (BATCH*NPOSP*4)                  // 2,911,232
#define WS_SELKEY (WS_SELIDX + BATCH*KTOP*4)
#define WS_LABELS (WS_SELKEY + BATCH*KTOP*4)

__device__ __forceinline__ float sigmoidf_ref(float x) {
    return 1.0f / (1.0f + expf(-x));
}

// ---------------------------------------------------------------------------
// Kernel A: conf key per (b,n). Valid conf ∈ (0.5,1) has float bits
// 0x3F000001..0x3F7FFFFF (exponent 0x7E) -> store low 24 bits (0 = invalid).
// Padded stride NPOSP; pad element zeroed (poisoned ws!).
// ---------------------------------------------------------------------------
__global__ __launch_bounds__(256) void k_extract(const float* __restrict__ p,
                                                 unsigned* __restrict__ keys) {
    const int n = blockIdx.x * 256 + threadIdx.x;
    const int b = blockIdx.y;
    if (n < NPOS) {
        float x = p[((size_t)b * NPOS + n) * ROW + 4];
        float cf = sigmoidf_ref(x);
        keys[(size_t)b * NPOSP + n] = (cf > 0.5f) ? (__float_as_uint(cf) & 0x00FFFFFFu) : 0u;
    } else if (n < NPOSP) {
        keys[(size_t)b * NPOSP + n] = 0u;   // pad must not look like a candidate
    }
}

// ---------------------------------------------------------------------------
// Kernel B: per-image exact top-300 (3x8-bit radix-select + bitonic sort),
// stable (key desc, index asc) to match lax.top_k tie semantics.
// 512 threads; uint4-vectorized sweeps; zero-keys aggregated (no bin-0 storm).
// ---------------------------------------------------------------------------
__global__ __launch_bounds__(512) void k_select(const unsigned* __restrict__ keys,
                                                int* __restrict__ sel_idx,
                                                unsigned* __restrict__ sel_key) {
    const int b = blockIdx.x;
    const int t = threadIdx.x;
    const int lane = t & 63;
    __shared__ unsigned h[256];
    __shared__ unsigned sc[256];
    __shared__ unsigned bcast_bin, bcast_R;
    __shared__ int cnt, ovf;
    __shared__ unsigned long long arr[KPAD];
    const unsigned* kb = keys + (size_t)b * NPOSP;
    const uint4* kb4 = reinterpret_cast<const uint4*>(kb);

    unsigned prefix = 0;
    unsigned R = KTOP;

    for (int pass = 0; pass < 3; ++pass) {
        const int shift = 16 - 8 * pass;
        if (t < 256) h[t] = 0;
        __syncthreads();
        int zc = 0;   // zero-key matches, aggregated (avoid same-address atomics)
        for (int i4 = t; i4 < N4P; i4 += 512) {
            uint4 u4 = kb4[i4];
            unsigned uu[4] = {u4.x, u4.y, u4.z, u4.w};
            #pragma unroll
            for (int c = 0; c < 4; ++c) {
                unsigned u = uu[c];
                bool match = (pass == 0) || ((u >> (shift + 8)) == prefix);
                if (match) {
                    if (u) atomicAdd(&h[(u >> shift) & 255], 1u);
                    else   ++zc;
                }
            }
        }
        #pragma unroll
        for (int d = 32; d; d >>= 1) zc += __shfl_xor(zc, d);
        if (lane == 0 && zc) atomicAdd(&h[0], (unsigned)zc);
        __syncthreads();
        // suffix-inclusive sum: sc[v] = sum_{w>=v} h[w]
        if (t < 256) sc[t] = h[t];
        __syncthreads();
        for (int off = 1; off < 256; off <<= 1) {
            unsigned add = (t < 256 && t + off < 256) ? sc[t + off] : 0u;
            __syncthreads();
            if (t < 256) sc[t] += add;
            __syncthreads();
        }
        if (t < 256) {
            unsigned snext = (t < 255) ? sc[t + 1] : 0u;
            if (sc[t] >= R && snext < R) { bcast_bin = (unsigned)t; bcast_R = R - snext; }
        }
        __syncthreads();
        prefix = (prefix << 8) | bcast_bin;
        R = bcast_R;
        __syncthreads();
    }
    const unsigned T = prefix;  // exact 300th 24-bit key

    if (t == 0) { cnt = 0; ovf = 0; }
    for (int e = t; e < KPAD; e += 512) arr[e] = 0ull;
    __syncthreads();
    for (int i4 = t; i4 < N4P; i4 += 512) {
        uint4 u4 = kb4[i4];
        unsigned uu[4] = {u4.x, u4.y, u4.z, u4.w};
        #pragma unroll
        for (int c = 0; c < 4; ++c) {
            unsigned u = uu[c];
            if (u >= T) {
                int n = i4 * 4 + c;
                int pos = atomicAdd(&cnt, 1);
                if (pos < KPAD) arr[pos] = ((unsigned long long)u << 32) | (unsigned)(~n);
                else ovf = 1;
            }
        }
    }
    __syncthreads();
    if (ovf) {  // degenerate tie storm (or T==0): strict-greaters, serial equals
        if (t == 0) cnt = 0;
        __syncthreads();
        for (int e = t; e < KPAD; e += 512) arr[e] = 0ull;
        __syncthreads();
        for (int n = t; n < NPOS; n += 512) {
            unsigned u = kb[n];
            if (u > T) {
                int pos = atomicAdd(&cnt, 1);
                if (pos < KPAD) arr[pos] = ((unsigned long long)u << 32) | (unsigned)(~n);
            }
        }
        __syncthreads();
        if (t == 0) {
            int c = min(cnt, KPAD - 1);   // proven <=299; min is insurance
            for (int n = 0; n < NPOS && c < KTOP; ++n)
                if (kb[n] == T) arr[c++] = ((unsigned long long)T << 32) | (unsigned)(~n);
        }
        __syncthreads();
    }
    // ascending bitonic sort of 512 u64; pads(0) first, real entries last
    for (unsigned kk = 2; kk <= KPAD; kk <<= 1)
        for (unsigned j = kk >> 1; j > 0; j >>= 1) {
            __syncthreads();
            unsigned e = (unsigned)t, partner = e ^ j;
            if (partner > e) {
                bool up = ((e & kk) == 0);
                unsigned long long a = arr[e], bb = arr[partner];
                if (up ? (a > bb) : (a < bb)) { arr[e] = bb; arr[partner] = a; }
            }
        }
    __syncthreads();
    if (t < KTOP) {
        unsigned long long v = arr[KPAD - 1 - t];  // descending
        sel_idx[b * KTOP + t] = (int)(~(unsigned)v);
        sel_key[b * KTOP + t] = (unsigned)(v >> 32);
    }
}

// ---------------------------------------------------------------------------
// Kernel C: gather+decode selected rows. One wave per (b,k). (proven; unchanged)
// ---------------------------------------------------------------------------
__global__ __launch_bounds__(256) void k_decode(const float* __restrict__ p,
                                                const float* __restrict__ ancs,
                                                const float* __restrict__ fsz,
                                                const int* __restrict__ sel_idx,
                                                int* __restrict__ labels,
                                                float* __restrict__ out) {
    const int wid = (int)((blockIdx.x * blockDim.x + threadIdx.x) >> 6);
    const int lane = threadIdx.x & 63;
    if (wid >= BATCH * KTOP) return;
    const int b = wid / KTOP, k = wid % KTOP;
    const int n = sel_idx[b * KTOP + k];
    const size_t base = ((size_t)b * NPOS + n) * ROW;

    float v1 = p[base + lane];
    float v2 = (lane < 21) ? p[base + 64 + lane] : -INFINITY;

    // class argmax (raw logits; sigmoid is monotone), ties -> lower class
    float bv = -INFINITY; int bc = 1 << 20;
    if (lane >= 5) { bv = v1; bc = lane - 5; }            // classes 0..58
    if (lane < 21) {
        int c2 = 59 + lane;                                // classes 59..79
        if (v2 > bv || (v2 == bv && c2 < bc)) { bv = v2; bc = c2; }
    }
    for (int d = 32; d; d >>= 1) {
        float ov = __shfl_xor(bv, d);
        int   oc = __shfl_xor(bc, d);
        if (ov > bv || (ov == bv && oc < bc)) { bv = ov; bc = oc; }
    }
    const int label = bc + 1;

    float t0 = __shfl(v1, 0), t1 = __shfl(v1, 1), t2 = __shfl(v1, 2), t3 = __shfl(v1, 3);
    if (lane == 0) {
        float f0 = fsz[(size_t)n * 2 + 0], f1 = fsz[(size_t)n * 2 + 1];
        float a0 = ancs[(size_t)n * 4 + 0], a1 = ancs[(size_t)n * 4 + 1];
        float a2 = ancs[(size_t)n * 4 + 2], a3 = ancs[(size_t)n * 4 + 3];
        float cx = sigmoidf_ref(t0) / f0 + a0;
        float cy = sigmoidf_ref(t1) / f1 + a1;
        float w  = expf(t2) * a2;
        float hh = expf(t3) * a3;
        float* ob = out + OFF_BOXES + (size_t)(b * KTOP + k) * 4;
        ob[0] = cx - w * 0.5f;
        ob[1] = cy - hh * 0.5f;
        ob[2] = cx + w * 0.5f;
        ob[3] = cy + hh * 0.5f;
        out[OFF_IDS + b * KTOP + k] = (float)b;
        labels[b * KTOP + k] = label;
    }
}

// ---------------------------------------------------------------------------
// Kernel D: per-image label-offset NMS. 512 threads; wave-cooperative ballot
// O-build (lanes cover 64 j's of a row in parallel); serial greedy scan.
// ---------------------------------------------------------------------------
__global__ __launch_bounds__(512) void k_nms(const float* __restrict__ boxes,
                                             const int* __restrict__ labels,
                                             const unsigned* __restrict__ sel_key,
                                             float* __restrict__ out) {
    const int b = blockIdx.x, t = threadIdx.x;
    const int lane = t & 63, wave = t >> 6;   // 8 waves
    __shared__ float4 bx4[KTOP];
    __shared__ float  area_s[KTOP];
    __shared__ float  score_s[KTOP];
    __shared__ int    lab_s[KTOP];
    __shared__ unsigned long long O[KTOP * 5];
    __shared__ unsigned long long vb[5];
    __shared__ unsigned long long kw[5];

    bool valid = false;
    if (t < KTOP) {
        const float* p4 = boxes + (size_t)(b * KTOP + t) * 4;
        int L = labels[b * KTOP + t];
        float off = (float)L * 4.0f;
        float l = p4[0] + off, tp = p4[1] + off, r = p4[2] + off, bt = p4[3] + off;
        bx4[t] = make_float4(l, tp, r, bt);
        area_s[t] = fmaxf(r - l, 0.0f) * fmaxf(bt - tp, 0.0f);
        lab_s[t] = L;
        unsigned key = sel_key[b * KTOP + t];
        valid = (key != 0u);                                 // conf > 0.5
        score_s[t] = __uint_as_float(key | 0x3F000000u);     // exact top_scores
    }
    unsigned long long vbw = __ballot(valid);
    if (lane == 0 && wave < 5) vb[wave] = vbw;
    __syncthreads();

    // overlap bitmask rows via ballot: row i, word q covers j in [64q, 64q+64)∩[0,i)
    for (int i = wave; i < KTOP; i += 8) {
        float4 bi = bx4[i];
        float  ai = area_s[i];
        int qmax = (i + 63) >> 6;   // words that can contain j < i
        for (int q = 0; q < 5; ++q) {
            unsigned long long w = 0ull;
            if (q < qmax) {
                int j = q * 64 + lane;
                bool pred = false;
                if (j < i) {
                    float4 bj = bx4[j];
                    float lt0 = fmaxf(bi.x, bj.x);
                    float lt1 = fmaxf(bi.y, bj.y);
                    float rb0 = fminf(bi.z, bj.z);
                    float rb1 = fminf(bi.w, bj.w);
                    float ww = fmaxf(rb0 - lt0, 0.0f);
                    float hh = fmaxf(rb1 - lt1, 0.0f);
                    float inter = ww * hh;
                    float iou = inter / (((ai + area_s[j]) - inter) + 1e-7f);
                    pred = iou > 0.3f;
                }
                w = __ballot(pred);
            }
            if (lane == 0) O[i * 5 + q] = w;
        }
    }
    __syncthreads();

    // serial greedy scan: wave 0, lanes 0..4 own keep-bit words, prefetch next row
    if (t < 64) {
        unsigned long long kwl = 0ull;
        unsigned long long vbl = (lane < 5) ? vb[lane] : 0ull;
        unsigned long long cur = (lane < 5) ? O[lane] : 0ull;
        for (int i = 0; i < KTOP; ++i) {
            unsigned long long nxt = (lane < 5 && i < KTOP - 1) ? O[(i + 1) * 5 + lane] : 0ull;
            bool sup = __any((cur & kwl) != 0ull);
            if (lane == (i >> 6)) {
                bool v = (vbl >> (i & 63)) & 1ull;
                if (v && !sup) kwl |= 1ull << (i & 63);
            }
            cur = nxt;
        }
        if (lane < 5) kw[lane] = kwl;
    }
    __syncthreads();

    if (t < KTOP) {
        bool kp = (kw[t >> 6] >> (t & 63)) & 1ull;
        out[OFF_SCORES + b * KTOP + t] = kp ? score_s[t] : 0.0f;
        out[OFF_LABELS + b * KTOP + t] = kp ? (float)lab_s[t] : 0.0f;
    }
}

// ---------------------------------------------------------------------------
extern "C" void kernel_launch(void* const* d_in, const int* in_sizes, int n_in,
                              void* d_out, int out_size, void* d_ws, size_t ws_size,
                              hipStream_t stream) {
    const float* p    = (const float*)d_in[0];   // [B,N,85]
    const float* ancs = (const float*)d_in[1];   // [N,4]
    const float* fsz  = (const float*)d_in[2];   // [N,2]
    float* out = (float*)d_out;

    char* w = (char*)d_ws;
    unsigned* keys    = (unsigned*)(w + WS_KEYS);
    int*      sel_idx = (int*)(w + WS_SELIDX);
    unsigned* sel_key = (unsigned*)(w + WS_SELKEY);
    int*      labels  = (int*)(w + WS_LABELS);

    hipLaunchKernelGGL(k_extract, dim3((NPOSP + 255) / 256, BATCH), dim3(256), 0, stream, p, keys);
    hipLaunchKernelGGL(k_select, dim3(BATCH), dim3(512), 0, stream, keys, sel_idx, sel_key);
    hipLaunchKernelGGL(k_decode, dim3((BATCH * KTOP + 3) / 4), dim3(256), 0, stream,
                       p, ancs, fsz, sel_idx, labels, out);
    hipLaunchKernelGGL(k_nms, dim3(BATCH), dim3(512), 0, stream, out + OFF_BOXES, labels, sel_key, out);
}

// Round 5
// 378.087 us; speedup vs baseline: 1.2226x; 1.0189x over previous
//
#include <hip/hip_runtime.h>
#include <hip/hip_bf16.h>

#pragma clang fp contract(off)

// ---------------- problem constants ----------------
#define BATCH 32
#define NPOS  22743          // sum f*f*3 over {19,38,76}
#define NPOSP 22744          // padded stride (16B-aligned uint4 rows); pad key = 0
#define N4P   (NPOSP/4)      // 5686 uint4 per image
#define ROW   85             // 5 + 80 classes
#define KTOP  300
#define KPAD  512
#define NBIN  1024           // keys are 23-bit; bin = key >> 13

// output layout (floats), concatenated in reference return order
#define OFF_IDS    0
#define OFF_BOXES  (BATCH*KTOP)                    // 9600
#define OFF_LABELS (OFF_BOXES + BATCH*KTOP*4)      // 48000
#define OFF_SCORES (OFF_LABELS + BATCH*KTOP)       // 57600

// workspace layout (bytes)
#define WS_KEYS   0
#define WS_SELIDX (BATCH*NPOSP*4)                  // 2,911,232
#define WS_SELKEY (WS_SELIDX + BATCH*KTOP*4)
#define WS_LABELS (WS_SELKEY + BATCH*KTOP*4)

__device__ __forceinline__ float sigmoidf_ref(float x) {
    return 1.0f / (1.0f + expf(-x));
}

// ---------------------------------------------------------------------------
// Kernel A: conf key per (b,n). Valid conf ∈ (0.5,1) has float bits
// 0x3F000001..0x3F7FFFFF (exponent 0x7E) -> store low 24 bits (0 = invalid).
// Padded stride NPOSP; pad element zeroed (poisoned ws!).
// ---------------------------------------------------------------------------
__global__ __launch_bounds__(256) void k_extract(const float* __restrict__ p,
                                                 unsigned* __restrict__ keys) {
    const int n = blockIdx.x * 256 + threadIdx.x;
    const int b = blockIdx.y;
    if (n < NPOS) {
        float x = p[((size_t)b * NPOS + n) * ROW + 4];
        float cf = sigmoidf_ref(x);
        keys[(size_t)b * NPOSP + n] = (cf > 0.5f) ? (__float_as_uint(cf) & 0x00FFFFFFu) : 0u;
    } else if (n < NPOSP) {
        keys[(size_t)b * NPOSP + n] = 0u;   // pad must not look like a candidate
    }
}

// ---------------------------------------------------------------------------
// Kernel B: per-image exact top-300, fast path = 2 sweeps:
//   sweep 1: 1024-bin histogram of key>>13 (rank-300 bin B is ~4-5 deep)
//   sweep 2: collect all keys >= (B<<13)  (≈304 candidates ≤ 512)
//   bitonic sort 512 desc by (key, ~n) -> exact stable top-300.
// Fallback (B==0 or >512 candidates; unreachable for this data): exact
// 3x8-bit radix select + strict-greater collect + serial equals.
// ---------------------------------------------------------------------------
__global__ __launch_bounds__(512) void k_select(const unsigned* __restrict__ keys,
                                                int* __restrict__ sel_idx,
                                                unsigned* __restrict__ sel_key) {
    const int b = blockIdx.x;
    const int t = threadIdx.x;
    const int lane = t & 63;
    __shared__ unsigned h[NBIN];
    __shared__ unsigned s512[512];
    __shared__ unsigned bcast_bin, bcast_G;
    __shared__ int cnt, ovf;
    __shared__ unsigned long long arr[KPAD];
    const unsigned* kb = keys + (size_t)b * NPOSP;
    const uint4* kb4 = reinterpret_cast<const uint4*>(kb);

    // ---- sweep 1: 1024-bin histogram (zeros wave-aggregated: no bin-0 storm) ----
    h[t] = 0;
    if (t < NBIN - 512) h[t + 512] = 0;
    __syncthreads();
    {
        int zc = 0;
        for (int i4 = t; i4 < N4P; i4 += 512) {
            uint4 u4 = kb4[i4];
            unsigned uu[4] = {u4.x, u4.y, u4.z, u4.w};
            #pragma unroll
            for (int c = 0; c < 4; ++c) {
                unsigned u = uu[c];
                if (u) atomicAdd(&h[u >> 13], 1u);
                else   ++zc;
            }
        }
        #pragma unroll
        for (int d = 32; d; d >>= 1) zc += __shfl_xor(zc, d);
        if (lane == 0 && zc) atomicAdd(&h[0], (unsigned)zc);
    }
    __syncthreads();
    // ---- find bin B containing rank-300; G = count in bins > B ----
    unsigned c0 = h[2 * t], c1 = h[2 * t + 1];
    s512[t] = c0 + c1;
    __syncthreads();
    for (int off = 1; off < 512; off <<= 1) {     // suffix-inclusive scan
        unsigned add = (t + off < 512) ? s512[t + off] : 0u;
        __syncthreads();
        s512[t] += add;
        __syncthreads();
    }
    {
        unsigned S = s512[t];                            // sum bins >= 2t
        unsigned Snext = (t < 511) ? s512[t + 1] : 0u;   // sum bins >= 2t+2
        if (S >= KTOP && Snext < KTOP) {                 // crossing in this chunk
            unsigned s1 = c1 + Snext;                    // sum bins >= 2t+1
            if (s1 >= KTOP) { bcast_bin = 2u * t + 1u; bcast_G = Snext; }
            else            { bcast_bin = 2u * t;      bcast_G = s1; }
        }
    }
    __syncthreads();
    const unsigned B = bcast_bin;

    bool fast_ok = false;
    if (B > 0) {
        const unsigned T = B << 13;
        if (t == 0) { cnt = 0; ovf = 0; }
        arr[t] = 0ull;
        __syncthreads();
        for (int i4 = t; i4 < N4P; i4 += 512) {
            uint4 u4 = kb4[i4];
            unsigned uu[4] = {u4.x, u4.y, u4.z, u4.w};
            #pragma unroll
            for (int c = 0; c < 4; ++c) {
                unsigned u = uu[c];
                if (u >= T) {
                    int n = i4 * 4 + c;
                    int pos = atomicAdd(&cnt, 1);
                    if (pos < KPAD) arr[pos] = ((unsigned long long)u << 32) | (unsigned)(~n);
                    else ovf = 1;
                }
            }
        }
        __syncthreads();
        fast_ok = (ovf == 0);
    }

    if (!fast_ok) {
        // ---- exact 3x8-bit radix select over 24-bit keys (block-uniform) ----
        unsigned prefix = 0, R = KTOP;
        for (int pass = 0; pass < 3; ++pass) {
            const int shift = 16 - 8 * pass;
            if (t < 256) h[t] = 0;
            __syncthreads();
            int zc2 = 0;
            for (int n = t; n < NPOSP; n += 512) {
                unsigned u = kb[n];
                bool match = (pass == 0) || ((u >> (shift + 8)) == prefix);
                if (match) {
                    if (u) atomicAdd(&h[(u >> shift) & 255], 1u);
                    else   ++zc2;
                }
            }
            #pragma unroll
            for (int d = 32; d; d >>= 1) zc2 += __shfl_xor(zc2, d);
            if (lane == 0 && zc2) atomicAdd(&h[0], (unsigned)zc2);
            __syncthreads();
            if (t < 256) s512[t] = h[t];
            __syncthreads();
            for (int off = 1; off < 256; off <<= 1) {
                unsigned add = (t < 256 && t + off < 256) ? s512[t + off] : 0u;
                __syncthreads();
                if (t < 256) s512[t] += add;
                __syncthreads();
            }
            if (t < 256) {
                unsigned snext = (t < 255) ? s512[t + 1] : 0u;
                if (s512[t] >= R && snext < R) { bcast_bin = (unsigned)t; bcast_G = R - snext; }
            }
            __syncthreads();
            prefix = (prefix << 8) | bcast_bin;
            R = bcast_G;
            __syncthreads();
        }
        const unsigned Tex = prefix;   // exact rank-300 key
        if (t == 0) cnt = 0;
        arr[t] = 0ull;
        __syncthreads();
        for (int n = t; n < NPOS; n += 512) {
            unsigned u = kb[n];
            if (u > Tex) {                       // strictly greater: <= 299 always
                int pos = atomicAdd(&cnt, 1);
                if (pos < KPAD) arr[pos] = ((unsigned long long)u << 32) | (unsigned)(~n);
            }
        }
        __syncthreads();
        if (t == 0) {                            // equals in index order up to 300
            int c = min(cnt, KPAD - 1);
            for (int n = 0; n < NPOS && c < KTOP; ++n)
                if (kb[n] == Tex) arr[c++] = ((unsigned long long)Tex << 32) | (unsigned)(~n);
        }
        __syncthreads();
    }

    // ---- ascending bitonic sort of 512 u64; pads(0) first, real entries last ----
    for (unsigned kk = 2; kk <= KPAD; kk <<= 1)
        for (unsigned j = kk >> 1; j > 0; j >>= 1) {
            __syncthreads();
            unsigned e = (unsigned)t, partner = e ^ j;
            if (partner > e) {
                bool up = ((e & kk) == 0);
                unsigned long long a = arr[e], bb = arr[partner];
                if (up ? (a > bb) : (a < bb)) { arr[e] = bb; arr[partner] = a; }
            }
        }
    __syncthreads();
    if (t < KTOP) {
        unsigned long long v = arr[KPAD - 1 - t];  // descending
        sel_idx[b * KTOP + t] = (int)(~(unsigned)v);
        sel_key[b * KTOP + t] = (unsigned)(v >> 32);
    }
}

// ---------------------------------------------------------------------------
// Kernel C: gather+decode selected rows. One wave per (b,k). (proven; unchanged)
// ---------------------------------------------------------------------------
__global__ __launch_bounds__(256) void k_decode(const float* __restrict__ p,
                                                const float* __restrict__ ancs,
                                                const float* __restrict__ fsz,
                                                const int* __restrict__ sel_idx,
                                                int* __restrict__ labels,
                                                float* __restrict__ out) {
    const int wid = (int)((blockIdx.x * blockDim.x + threadIdx.x) >> 6);
    const int lane = threadIdx.x & 63;
    if (wid >= BATCH * KTOP) return;
    const int b = wid / KTOP, k = wid % KTOP;
    const int n = sel_idx[b * KTOP + k];
    const size_t base = ((size_t)b * NPOS + n) * ROW;

    float v1 = p[base + lane];
    float v2 = (lane < 21) ? p[base + 64 + lane] : -INFINITY;

    // class argmax (raw logits; sigmoid is monotone), ties -> lower class
    float bv = -INFINITY; int bc = 1 << 20;
    if (lane >= 5) { bv = v1; bc = lane - 5; }            // classes 0..58
    if (lane < 21) {
        int c2 = 59 + lane;                                // classes 59..79
        if (v2 > bv || (v2 == bv && c2 < bc)) { bv = v2; bc = c2; }
    }
    for (int d = 32; d; d >>= 1) {
        float ov = __shfl_xor(bv, d);
        int   oc = __shfl_xor(bc, d);
        if (ov > bv || (ov == bv && oc < bc)) { bv = ov; bc = oc; }
    }
    const int label = bc + 1;

    float t0 = __shfl(v1, 0), t1 = __shfl(v1, 1), t2 = __shfl(v1, 2), t3 = __shfl(v1, 3);
    if (lane == 0) {
        float f0 = fsz[(size_t)n * 2 + 0], f1 = fsz[(size_t)n * 2 + 1];
        float a0 = ancs[(size_t)n * 4 + 0], a1 = ancs[(size_t)n * 4 + 1];
        float a2 = ancs[(size_t)n * 4 + 2], a3 = ancs[(size_t)n * 4 + 3];
        float cx = sigmoidf_ref(t0) / f0 + a0;
        float cy = sigmoidf_ref(t1) / f1 + a1;
        float w  = expf(t2) * a2;
        float hh = expf(t3) * a3;
        float* ob = out + OFF_BOXES + (size_t)(b * KTOP + k) * 4;
        ob[0] = cx - w * 0.5f;
        ob[1] = cy - hh * 0.5f;
        ob[2] = cx + w * 0.5f;
        ob[3] = cy + hh * 0.5f;
        out[OFF_IDS + b * KTOP + k] = (float)b;
        labels[b * KTOP + k] = label;
    }
}

// ---------------------------------------------------------------------------
// Kernel D: per-image label-offset NMS. 512 threads; wave-cooperative ballot
// O-build (lanes cover 64 j's of a row in parallel); serial greedy scan.
// (proven; unchanged)
// ---------------------------------------------------------------------------
__global__ __launch_bounds__(512) void k_nms(const float* __restrict__ boxes,
                                             const int* __restrict__ labels,
                                             const unsigned* __restrict__ sel_key,
                                             float* __restrict__ out) {
    const int b = blockIdx.x, t = threadIdx.x;
    const int lane = t & 63, wave = t >> 6;   // 8 waves
    __shared__ float4 bx4[KTOP];
    __shared__ float  area_s[KTOP];
    __shared__ float  score_s[KTOP];
    __shared__ int    lab_s[KTOP];
    __shared__ unsigned long long O[KTOP * 5];
    __shared__ unsigned long long vb[5];
    __shared__ unsigned long long kw[5];

    bool valid = false;
    if (t < KTOP) {
        const float* p4 = boxes + (size_t)(b * KTOP + t) * 4;
        int L = labels[b * KTOP + t];
        float off = (float)L * 4.0f;
        float l = p4[0] + off, tp = p4[1] + off, r = p4[2] + off, bt = p4[3] + off;
        bx4[t] = make_float4(l, tp, r, bt);
        area_s[t] = fmaxf(r - l, 0.0f) * fmaxf(bt - tp, 0.0f);
        lab_s[t] = L;
        unsigned key = sel_key[b * KTOP + t];
        valid = (key != 0u);                                 // conf > 0.5
        score_s[t] = __uint_as_float(key | 0x3F000000u);     // exact top_scores
    }
    unsigned long long vbw = __ballot(valid);
    if (lane == 0 && wave < 5) vb[wave] = vbw;
    __syncthreads();

    // overlap bitmask rows via ballot: row i, word q covers j in [64q, 64q+64)∩[0,i)
    for (int i = wave; i < KTOP; i += 8) {
        float4 bi = bx4[i];
        float  ai = area_s[i];
        int qmax = (i + 63) >> 6;   // words that can contain j < i
        for (int q = 0; q < 5; ++q) {
            unsigned long long w = 0ull;
            if (q < qmax) {
                int j = q * 64 + lane;
                bool pred = false;
                if (j < i) {
                    float4 bj = bx4[j];
                    float lt0 = fmaxf(bi.x, bj.x);
                    float lt1 = fmaxf(bi.y, bj.y);
                    float rb0 = fminf(bi.z, bj.z);
                    float rb1 = fminf(bi.w, bj.w);
                    float ww = fmaxf(rb0 - lt0, 0.0f);
                    float hh = fmaxf(rb1 - lt1, 0.0f);
                    float inter = ww * hh;
                    float iou = inter / (((ai + area_s[j]) - inter) + 1e-7f);
                    pred = iou > 0.3f;
                }
                w = __ballot(pred);
            }
            if (lane == 0) O[i * 5 + q] = w;
        }
    }
    __syncthreads();

    // serial greedy scan: wave 0, lanes 0..4 own keep-bit words, prefetch next row
    if (t < 64) {
        unsigned long long kwl = 0ull;
        unsigned long long vbl = (lane < 5) ? vb[lane] : 0ull;
        unsigned long long cur = (lane < 5) ? O[lane] : 0ull;
        for (int i = 0; i < KTOP; ++i) {
            unsigned long long nxt = (lane < 5 && i < KTOP - 1) ? O[(i + 1) * 5 + lane] : 0ull;
            bool sup = __any((cur & kwl) != 0ull);
            if (lane == (i >> 6)) {
                bool v = (vbl >> (i & 63)) & 1ull;
                if (v && !sup) kwl |= 1ull << (i & 63);
            }
            cur = nxt;
        }
        if (lane < 5) kw[lane] = kwl;
    }
    __syncthreads();

    if (t < KTOP) {
        bool kp = (kw[t >> 6] >> (t & 63)) & 1ull;
        out[OFF_SCORES + b * KTOP + t] = kp ? score_s[t] : 0.0f;
        out[OFF_LABELS + b * KTOP + t] = kp ? (float)lab_s[t] : 0.0f;
    }
}

// ---------------------------------------------------------------------------
extern "C" void kernel_launch(void* const* d_in, const int* in_sizes, int n_in,
                              void* d_out, int out_size, void* d_ws, size_t ws_size,
                              hipStream_t stream) {
    const float* p    = (const float*)d_in[0];   // [B,N,85]
    const float* ancs = (const float*)d_in[1];   // [N,4]
    const float* fsz  = (const float*)d_in[2];   // [N,2]
    float* out = (float*)d_out;

    char* w = (char*)d_ws;
    unsigned* keys    = (unsigned*)(w + WS_KEYS);
    int*      sel_idx = (int*)(w + WS_SELIDX);
    unsigned* sel_key = (unsigned*)(w + WS_SELKEY);
    int*      labels  = (int*)(w + WS_LABELS);

    hipLaunchKernelGGL(k_extract, dim3((NPOSP + 255) / 256, BATCH), dim3(256), 0, stream, p, keys);
    hipLaunchKernelGGL(k_select, dim3(BATCH), dim3(512), 0, stream, keys, sel_idx, sel_key);
    hipLaunchKernelGGL(k_decode, dim3((BATCH * KTOP + 3) / 4), dim3(256), 0, stream,
                       p, ancs, fsz, sel_idx, labels, out);
    hipLaunchKernelGGL(k_nms, dim3(BATCH), dim3(512), 0, stream, out + OFF_BOXES, labels, sel_key, out);
}

// Round 6
// 375.958 us; speedup vs baseline: 1.2296x; 1.0057x over previous
//
#include <hip/hip_runtime.h>
#include <hip/hip_bf16.h>

#pragma clang fp contract(off)

// ---------------- problem constants ----------------
#define BATCH 32
#define NPOS  22743          // sum f*f*3 over {19,38,76}
#define NPOSP 22744          // padded stride (16B-aligned uint4 rows); pad key = 0
#define N4P   (NPOSP/4)      // 5686 uint4 per image
#define ROW   85             // 5 + 80 classes
#define KTOP  300
#define KPAD  512
#define NBIN  1024           // keys are 23-bit; bin = key >> 13

// output layout (floats), concatenated in reference return order
#define OFF_IDS    0
#define OFF_BOXES  (BATCH*KTOP)                    // 9600
#define OFF_LABELS (OFF_BOXES + BATCH*KTOP*4)      // 48000
#define OFF_SCORES (OFF_LABELS + BATCH*KTOP)       // 57600

// workspace layout (bytes)
#define WS_KEYS   0
#define WS_SELIDX (BATCH*NPOSP*4)                  // 2,911,232
#define WS_SELKEY (WS_SELIDX + BATCH*KTOP*4)
#define WS_LABELS (WS_SELKEY + BATCH*KTOP*4)

__device__ __forceinline__ float sigmoidf_ref(float x) {
    return 1.0f / (1.0f + expf(-x));
}

// ---------------------------------------------------------------------------
// Kernel A: conf key per (b,n). Valid conf ∈ (0.5,1) has float bits
// 0x3F000001..0x3F7FFFFF (exponent 0x7E) -> store low 24 bits (0 = invalid).
// Padded stride NPOSP; pad element zeroed (poisoned ws!).
// ---------------------------------------------------------------------------
__global__ __launch_bounds__(256) void k_extract(const float* __restrict__ p,
                                                 unsigned* __restrict__ keys) {
    const int n = blockIdx.x * 256 + threadIdx.x;
    const int b = blockIdx.y;
    if (n < NPOS) {
        float x = p[((size_t)b * NPOS + n) * ROW + 4];
        float cf = sigmoidf_ref(x);
        keys[(size_t)b * NPOSP + n] = (cf > 0.5f) ? (__float_as_uint(cf) & 0x00FFFFFFu) : 0u;
    } else if (n < NPOSP) {
        keys[(size_t)b * NPOSP + n] = 0u;   // pad must not look like a candidate
    }
}

// ---------------------------------------------------------------------------
// Kernel B: per-image exact top-300, fast path = 2 sweeps:
//   sweep 1: 1024-bin histogram of key>>13 (rank-300 bin B is ~4-5 deep)
//   sweep 2: collect all keys >= (B<<13)  (≈304 candidates ≤ 512)
//   then barrier-free rank-scatter: rank(v) = #{w > v} over u64 (key,~n)
//   -> exact stable top-300 (replaces the former 45-barrier bitonic sort).
// Fallback (B==0 or >512 candidates; unreachable for this data): exact
// 3x8-bit radix select + strict-greater collect + serial equals.
// ---------------------------------------------------------------------------
__global__ __launch_bounds__(512) void k_select(const unsigned* __restrict__ keys,
                                                int* __restrict__ sel_idx,
                                                unsigned* __restrict__ sel_key) {
    const int b = blockIdx.x;
    const int t = threadIdx.x;
    const int lane = t & 63;
    __shared__ unsigned h[NBIN];
    __shared__ unsigned s512[512];
    __shared__ unsigned bcast_bin, bcast_G;
    __shared__ int cnt, ovf;
    __shared__ unsigned long long arr[KPAD];
    const unsigned* kb = keys + (size_t)b * NPOSP;
    const uint4* kb4 = reinterpret_cast<const uint4*>(kb);

    // ---- sweep 1: 1024-bin histogram (zeros wave-aggregated: no bin-0 storm) ----
    h[t] = 0;
    if (t < NBIN - 512) h[t + 512] = 0;
    __syncthreads();
    {
        int zc = 0;
        for (int i4 = t; i4 < N4P; i4 += 512) {
            uint4 u4 = kb4[i4];
            unsigned uu[4] = {u4.x, u4.y, u4.z, u4.w};
            #pragma unroll
            for (int c = 0; c < 4; ++c) {
                unsigned u = uu[c];
                if (u) atomicAdd(&h[u >> 13], 1u);
                else   ++zc;
            }
        }
        #pragma unroll
        for (int d = 32; d; d >>= 1) zc += __shfl_xor(zc, d);
        if (lane == 0 && zc) atomicAdd(&h[0], (unsigned)zc);
    }
    __syncthreads();
    // ---- find bin B containing rank-300; G = count in bins > B ----
    unsigned c0 = h[2 * t], c1 = h[2 * t + 1];
    s512[t] = c0 + c1;
    __syncthreads();
    for (int off = 1; off < 512; off <<= 1) {     // suffix-inclusive scan
        unsigned add = (t + off < 512) ? s512[t + off] : 0u;
        __syncthreads();
        s512[t] += add;
        __syncthreads();
    }
    {
        unsigned S = s512[t];                            // sum bins >= 2t
        unsigned Snext = (t < 511) ? s512[t + 1] : 0u;   // sum bins >= 2t+2
        if (S >= KTOP && Snext < KTOP) {                 // crossing in this chunk
            unsigned s1 = c1 + Snext;                    // sum bins >= 2t+1
            if (s1 >= KTOP) { bcast_bin = 2u * t + 1u; bcast_G = Snext; }
            else            { bcast_bin = 2u * t;      bcast_G = s1; }
        }
    }
    __syncthreads();
    const unsigned B = bcast_bin;

    bool fast_ok = false;
    if (B > 0) {
        const unsigned T = B << 13;
        if (t == 0) { cnt = 0; ovf = 0; }
        arr[t] = 0ull;
        __syncthreads();
        for (int i4 = t; i4 < N4P; i4 += 512) {
            uint4 u4 = kb4[i4];
            unsigned uu[4] = {u4.x, u4.y, u4.z, u4.w};
            #pragma unroll
            for (int c = 0; c < 4; ++c) {
                unsigned u = uu[c];
                if (u >= T) {
                    int n = i4 * 4 + c;
                    int pos = atomicAdd(&cnt, 1);
                    if (pos < KPAD) arr[pos] = ((unsigned long long)u << 32) | (unsigned)(~n);
                    else ovf = 1;
                }
            }
        }
        __syncthreads();
        fast_ok = (ovf == 0);
    }

    if (!fast_ok) {
        // ---- exact 3x8-bit radix select over 24-bit keys (block-uniform) ----
        unsigned prefix = 0, R = KTOP;
        for (int pass = 0; pass < 3; ++pass) {
            const int shift = 16 - 8 * pass;
            if (t < 256) h[t] = 0;
            __syncthreads();
            int zc2 = 0;
            for (int n = t; n < NPOSP; n += 512) {
                unsigned u = kb[n];
                bool match = (pass == 0) || ((u >> (shift + 8)) == prefix);
                if (match) {
                    if (u) atomicAdd(&h[(u >> shift) & 255], 1u);
                    else   ++zc2;
                }
            }
            #pragma unroll
            for (int d = 32; d; d >>= 1) zc2 += __shfl_xor(zc2, d);
            if (lane == 0 && zc2) atomicAdd(&h[0], (unsigned)zc2);
            __syncthreads();
            if (t < 256) s512[t] = h[t];
            __syncthreads();
            for (int off = 1; off < 256; off <<= 1) {
                unsigned add = (t < 256 && t + off < 256) ? s512[t + off] : 0u;
                __syncthreads();
                if (t < 256) s512[t] += add;
                __syncthreads();
            }
            if (t < 256) {
                unsigned snext = (t < 255) ? s512[t + 1] : 0u;
                if (s512[t] >= R && snext < R) { bcast_bin = (unsigned)t; bcast_G = R - snext; }
            }
            __syncthreads();
            prefix = (prefix << 8) | bcast_bin;
            R = bcast_G;
            __syncthreads();
        }
        const unsigned Tex = prefix;   // exact rank-300 key
        if (t == 0) cnt = 0;
        arr[t] = 0ull;
        __syncthreads();
        for (int n = t; n < NPOS; n += 512) {
            unsigned u = kb[n];
            if (u > Tex) {                       // strictly greater: <= 299 always
                int pos = atomicAdd(&cnt, 1);
                if (pos < KPAD) arr[pos] = ((unsigned long long)u << 32) | (unsigned)(~n);
            }
        }
        __syncthreads();
        if (t == 0) {                            // equals in index order up to 300
            int c = min(cnt, KPAD - 1);
            for (int n = 0; n < NPOS && c < KTOP; ++n)
                if (kb[n] == Tex) arr[c++] = ((unsigned long long)Tex << 32) | (unsigned)(~n);
            cnt = c;                             // exactly KTOP real entries
        }
        __syncthreads();
    }

    // ---- barrier-free rank-scatter (replaces bitonic sort) ----
    // u64 (key<<32 | ~n) values are unique -> rank is exact and stable
    // (key desc, index asc). Both paths guarantee cnt >= KTOP real entries.
    if (t < KTOP) {                      // insurance init (unreachable case)
        sel_idx[b * KTOP + t] = 0;
        sel_key[b * KTOP + t] = 0u;
    }
    __syncthreads();                     // order init before scatter (block fence)
    {
        const int M = min(cnt, KPAD);
        unsigned long long mine = (t < M) ? arr[t] : 0ull;
        int rank = 0;
        #pragma unroll 4
        for (int j = 0; j < M; ++j) rank += (arr[j] > mine) ? 1 : 0;
        if (t < M && rank < KTOP) {
            sel_idx[b * KTOP + rank] = (int)(~(unsigned)mine);
            sel_key[b * KTOP + rank] = (unsigned)(mine >> 32);
        }
    }
}

// ---------------------------------------------------------------------------
// Kernel C: gather+decode selected rows. One wave per (b,k). (proven; unchanged)
// ---------------------------------------------------------------------------
__global__ __launch_bounds__(256) void k_decode(const float* __restrict__ p,
                                                const float* __restrict__ ancs,
                                                const float* __restrict__ fsz,
                                                const int* __restrict__ sel_idx,
                                                int* __restrict__ labels,
                                                float* __restrict__ out) {
    const int wid = (int)((blockIdx.x * blockDim.x + threadIdx.x) >> 6);
    const int lane = threadIdx.x & 63;
    if (wid >= BATCH * KTOP) return;
    const int b = wid / KTOP, k = wid % KTOP;
    const int n = sel_idx[b * KTOP + k];
    const size_t base = ((size_t)b * NPOS + n) * ROW;

    float v1 = p[base + lane];
    float v2 = (lane < 21) ? p[base + 64 + lane] : -INFINITY;

    // class argmax (raw logits; sigmoid is monotone), ties -> lower class
    float bv = -INFINITY; int bc = 1 << 20;
    if (lane >= 5) { bv = v1; bc = lane - 5; }            // classes 0..58
    if (lane < 21) {
        int c2 = 59 + lane;                                // classes 59..79
        if (v2 > bv || (v2 == bv && c2 < bc)) { bv = v2; bc = c2; }
    }
    for (int d = 32; d; d >>= 1) {
        float ov = __shfl_xor(bv, d);
        int   oc = __shfl_xor(bc, d);
        if (ov > bv || (ov == bv && oc < bc)) { bv = ov; bc = oc; }
    }
    const int label = bc + 1;

    float t0 = __shfl(v1, 0), t1 = __shfl(v1, 1), t2 = __shfl(v1, 2), t3 = __shfl(v1, 3);
    if (lane == 0) {
        float f0 = fsz[(size_t)n * 2 + 0], f1 = fsz[(size_t)n * 2 + 1];
        float a0 = ancs[(size_t)n * 4 + 0], a1 = ancs[(size_t)n * 4 + 1];
        float a2 = ancs[(size_t)n * 4 + 2], a3 = ancs[(size_t)n * 4 + 3];
        float cx = sigmoidf_ref(t0) / f0 + a0;
        float cy = sigmoidf_ref(t1) / f1 + a1;
        float w  = expf(t2) * a2;
        float hh = expf(t3) * a3;
        float* ob = out + OFF_BOXES + (size_t)(b * KTOP + k) * 4;
        ob[0] = cx - w * 0.5f;
        ob[1] = cy - hh * 0.5f;
        ob[2] = cx + w * 0.5f;
        ob[3] = cy + hh * 0.5f;
        out[OFF_IDS + b * KTOP + k] = (float)b;
        labels[b * KTOP + k] = label;
    }
}

// ---------------------------------------------------------------------------
// Kernel D: per-image label-offset NMS. 512 threads; wave-cooperative ballot
// O-build (lanes cover 64 j's of a row in parallel); serial greedy scan.
// (proven; unchanged)
// ---------------------------------------------------------------------------
__global__ __launch_bounds__(512) void k_nms(const float* __restrict__ boxes,
                                             const int* __restrict__ labels,
                                             const unsigned* __restrict__ sel_key,
                                             float* __restrict__ out) {
    const int b = blockIdx.x, t = threadIdx.x;
    const int lane = t & 63, wave = t >> 6;   // 8 waves
    __shared__ float4 bx4[KTOP];
    __shared__ float  area_s[KTOP];
    __shared__ float  score_s[KTOP];
    __shared__ int    lab_s[KTOP];
    __shared__ unsigned long long O[KTOP * 5];
    __shared__ unsigned long long vb[5];
    __shared__ unsigned long long kw[5];

    bool valid = false;
    if (t < KTOP) {
        const float* p4 = boxes + (size_t)(b * KTOP + t) * 4;
        int L = labels[b * KTOP + t];
        float off = (float)L * 4.0f;
        float l = p4[0] + off, tp = p4[1] + off, r = p4[2] + off, bt = p4[3] + off;
        bx4[t] = make_float4(l, tp, r, bt);
        area_s[t] = fmaxf(r - l, 0.0f) * fmaxf(bt - tp, 0.0f);
        lab_s[t] = L;
        unsigned key = sel_key[b * KTOP + t];
        valid = (key != 0u);                                 // conf > 0.5
        score_s[t] = __uint_as_float(key | 0x3F000000u);     // exact top_scores
    }
    unsigned long long vbw = __ballot(valid);
    if (lane == 0 && wave < 5) vb[wave] = vbw;
    __syncthreads();

    // overlap bitmask rows via ballot: row i, word q covers j in [64q, 64q+64)∩[0,i)
    for (int i = wave; i < KTOP; i += 8) {
        float4 bi = bx4[i];
        float  ai = area_s[i];
        int qmax = (i + 63) >> 6;   // words that can contain j < i
        for (int q = 0; q < 5; ++q) {
            unsigned long long w = 0ull;
            if (q < qmax) {
                int j = q * 64 + lane;
                bool pred = false;
                if (j < i) {
                    float4 bj = bx4[j];
                    float lt0 = fmaxf(bi.x, bj.x);
                    float lt1 = fmaxf(bi.y, bj.y);
                    float rb0 = fminf(bi.z, bj.z);
                    float rb1 = fminf(bi.w, bj.w);
                    float ww = fmaxf(rb0 - lt0, 0.0f);
                    float hh = fmaxf(rb1 - lt1, 0.0f);
                    float inter = ww * hh;
                    float iou = inter / (((ai + area_s[j]) - inter) + 1e-7f);
                    pred = iou > 0.3f;
                }
                w = __ballot(pred);
            }
            if (lane == 0) O[i * 5 + q] = w;
        }
    }
    __syncthreads();

    // serial greedy scan: wave 0, lanes 0..4 own keep-bit words, prefetch next row
    if (t < 64) {
        unsigned long long kwl = 0ull;
        unsigned long long vbl = (lane < 5) ? vb[lane] : 0ull;
        unsigned long long cur = (lane < 5) ? O[lane] : 0ull;
        for (int i = 0; i < KTOP; ++i) {
            unsigned long long nxt = (lane < 5 && i < KTOP - 1) ? O[(i + 1) * 5 + lane] : 0ull;
            bool sup = __any((cur & kwl) != 0ull);
            if (lane == (i >> 6)) {
                bool v = (vbl >> (i & 63)) & 1ull;
                if (v && !sup) kwl |= 1ull << (i & 63);
            }
            cur = nxt;
        }
        if (lane < 5) kw[lane] = kwl;
    }
    __syncthreads();

    if (t < KTOP) {
        bool kp = (kw[t >> 6] >> (t & 63)) & 1ull;
        out[OFF_SCORES + b * KTOP + t] = kp ? score_s[t] : 0.0f;
        out[OFF_LABELS + b * KTOP + t] = kp ? (float)lab_s[t] : 0.0f;
    }
}

// ---------------------------------------------------------------------------
extern "C" void kernel_launch(void* const* d_in, const int* in_sizes, int n_in,
                              void* d_out, int out_size, void* d_ws, size_t ws_size,
                              hipStream_t stream) {
    const float* p    = (const float*)d_in[0];   // [B,N,85]
    const float* ancs = (const float*)d_in[1];   // [N,4]
    const float* fsz  = (const float*)d_in[2];   // [N,2]
    float* out = (float*)d_out;

    char* w = (char*)d_ws;
    unsigned* keys    = (unsigned*)(w + WS_KEYS);
    int*      sel_idx = (int*)(w + WS_SELIDX);
    unsigned* sel_key = (unsigned*)(w + WS_SELKEY);
    int*      labels  = (int*)(w + WS_LABELS);

    hipLaunchKernelGGL(k_extract, dim3((NPOSP + 255) / 256, BATCH), dim3(256), 0, stream, p, keys);
    hipLaunchKernelGGL(k_select, dim3(BATCH), dim3(512), 0, stream, keys, sel_idx, sel_key);
    hipLaunchKernelGGL(k_decode, dim3((BATCH * KTOP + 3) / 4), dim3(256), 0, stream,
                       p, ancs, fsz, sel_idx, labels, out);
    hipLaunchKernelGGL(k_nms, dim3(BATCH), dim3(512), 0, stream, out + OFF_BOXES, labels, sel_key, out);
}